// Round 19
// baseline (150.628 us; speedup 1.0000x reference)
//
#include <hip/hip_runtime.h>
#include <hip/hip_bf16.h>
#include <math.h>

// ---------------------------------------------------------------------------
// MLPConv4d via bf16 MFMA implicit GEMM (v15 = r18 champion + conv1 split-K).
// conv1_part: x -> fp32 partials (atomicAdd into h32[64][16^4]); 2 ci-groups
//   of 8; slab 8x2500 shorts = 40 KB -> 4 blocks/CU = 16 waves (was 2/8).
// gelu_pack: h32 + b1 -> GELU -> hpad[64][18^4] bf16 (zero shell).
// conv2: unchanged r18 (pad-20 slab, 4 blocks/CU, split-K atomics, swizzle).
// K layout: k' = grp*4 + k4; grp<27; k4=3 slots and k'>=108 are ZERO weights.
// Slab per ci: [i1 5][i2 5][i3 5][i4 20(pad)] bf16 = 2500 shorts (5000 B).
// B-frag(sp, ks): lane(n16,hi) reads groups g = 8ks+2hi+{0,1} (clamp 26):
//   2x b32 at slab + fpb(sp) + kof(g) + {0,4} (merge->ds_read2_b32).
// K-loop: barrier-free; F ping-pong, A distance-2, setprio around MFMA.
// XCD swizzle on all tiled kernels (r18: halved FETCH via L2 sharing).
// ---------------------------------------------------------------------------

typedef __attribute__((ext_vector_type(8))) short short8;
typedef __attribute__((ext_vector_type(4))) float f32x4;
typedef __attribute__((ext_vector_type(4))) unsigned int uint4v;

__device__ __forceinline__ unsigned short f2bf(float v) {
    __hip_bfloat16 b = __float2bfloat16(v);
    return *(unsigned short*)&b;
}

// ---- fused setup: prepack w1/w2, bias-init out, zero hpad, zero h32 --------
__global__ void setup_kernel(const float* __restrict__ w1, const float* __restrict__ w2,
                             const float* __restrict__ b2,
                             unsigned short* __restrict__ w1p, unsigned short* __restrict__ w2p,
                             uint4v* __restrict__ hz, uint4v* __restrict__ h32z,
                             float* __restrict__ out) {
    int b = blockIdx.x, tid = threadIdx.x;
    if (b < 544) {                       // w1p: 16*64*136 = 139264 = 544*256
        int i = b * 256 + tid;
        int kp = i % 136, co = (i / 136) & 63, ci = i / 8704;
        float v = 0.f;
        if (kp < 108 && (kp & 3) < 3) v = w1[(co * 16 + ci) * 81 + (kp >> 2) * 3 + (kp & 3)];
        w1p[i] = f2bf(v);
    } else if (b < 1088) {               // w2p: 64*16*136 = 139264
        int i = (b - 544) * 256 + tid;
        int kp = i % 136, co = (i / 136) & 15, ci = i / 2176;
        float v = 0.f;
        if (kp < 108 && (kp & 3) < 3) v = w2[(co * 64 + ci) * 81 + (kp >> 2) * 3 + (kp & 3)];
        w2p[i] = f2bf(v);
    } else if (b < 1344) {               // out = bias: 65536
        int i = (b - 1088) * 256 + tid;
        out[i] = b2[i >> 12];
    } else if (b < 4096) {               // zero hpad: 839808 uint4
        int i = (b - 1344) * 256 + tid;  // 2752*256 = 704512
        hz[i] = (uint4v){0, 0, 0, 0};
        int j = i + 704512;
        if (j < 839808) hz[j] = (uint4v){0, 0, 0, 0};
    } else {                             // zero h32: 1,048,576 uint4 (16 MB)
        int i = (b - 4096) * 256 + tid;
        h32z[i] = (uint4v){0, 0, 0, 0};
    }
}

// ---- gelu_pack: h32 + bias -> exact GELU -> hpad interior ------------------
__global__ void gelu_pack(const float* __restrict__ h32, const float* __restrict__ b1,
                          unsigned short* __restrict__ hpad) {
    int i = blockIdx.x * 256 + threadIdx.x;     // 4,194,304
    int co = i >> 16;
    int sp = i & 65535;
    int o1 = sp >> 12, o2 = (sp >> 8) & 15, o3 = (sp >> 4) & 15, o4 = sp & 15;
    float v = h32[i] + b1[co];
    v = 0.5f * v * (1.f + erff(v * 0.70710678118654752f));
    hpad[(size_t)co * 104976 + (o1 + 1) * 5832 + (o2 + 1) * 324 + (o3 + 1) * 18 + (o4 + 1)] = f2bf(v);
}

// ---------------- conv1_part: split-K, barrier-free K-loop ------------------
// Block: sp 64 = (2,2,2,8), 64 co, 8 ci (cig 0/1). Grid 2048, 256 thr, 40 KB.
// Wave wv: sp-tiles 2(wv>>1)+{0,1}, co-tiles 2(wv&1)+{0,1}; 16 MFMA/ci.
// Epilogue: fp32 atomicAdd partials into h32 (each address hit exactly 2x).
__global__ __launch_bounds__(256) void conv1_part(
        const float* __restrict__ x, const unsigned short* __restrict__ w1p,
        float* __restrict__ h32) {
    __shared__ unsigned short sX[20000];   // [ci 8][2500] = 40000 B

    const int tid = threadIdx.x;
    const int braw = blockIdx.x;
    const int bid = ((braw & 7) << 8) | (braw >> 3);   // XCD swizzle, 2048 blocks
    const int tile = bid & 1023, cig = bid >> 10;
    const int cb = cig * 8;
    const int t4 = tile & 1, t3 = (tile >> 1) & 7, t2 = (tile >> 4) & 7, t1 = tile >> 7;
    const int bo1 = 2 * t1, bo2 = 2 * t2, bo3 = 2 * t3, bo4 = 8 * t4;
    const int g1b = 2 * bo1 - 1, g2b = 2 * bo2 - 1, g3b = 2 * bo3 - 1, g4b = 2 * bo4 - 1;

    // ---- staging slots: 1125 u32-units/ci (2 i4 elems), u = tid + 256r, r<5
    int offs[5], swb[5];
    unsigned mka = 0, mkb = 0;
#pragma unroll
    for (int r = 0; r < 5; ++r) {
        int u = tid + 256 * r;
        bool uok = u < 1125;
        int uu = uok ? u : 0;
        int p = uu % 9, q = uu / 9;
        int i3 = q % 5; q /= 5;
        int i2 = q % 5; int i1 = q / 5;
        int g1 = g1b + i1, g2 = g2b + i2, g3 = g3b + i3;
        bool ok123 = uok & ((unsigned)g1 < 32u) & ((unsigned)g2 < 32u) & ((unsigned)g3 < 32u);
        int g4a = g4b + 2 * p;
        offs[r] = ((g1 * 32 + g2) * 32 + g3) * 32 + g4a;
        if (ok123 && (unsigned)g4a < 32u) mka |= 1u << r;
        if (ok123 && (unsigned)(g4a + 1) < 32u) mkb |= 1u << r;
        swb[r] = 2 * (((i1 * 5 + i2) * 5 + i3) * 20 + 2 * p);
    }

    auto gatherX = [&](int ci, float (&a)[5], float (&b)[5]) {
        const float* xc = x + (size_t)ci * 1048576;
#pragma unroll
        for (int r = 0; r < 5; ++r) {
            float va = 0.f, vb = 0.f;
            if ((mka >> r) & 1) va = xc[offs[r]];
            if ((mkb >> r) & 1) vb = xc[offs[r] + 1];
            a[r] = va; b[r] = vb;
        }
    };
    auto writeSlab = [&](int s, const float (&a)[5], const float (&b)[5]) {
        char* slab = (char*)sX + s * 5000;
#pragma unroll
        for (int r = 0; r < 4; ++r)
            *(unsigned*)(slab + swb[r]) = (unsigned)f2bf(a[r]) | ((unsigned)f2bf(b[r]) << 16);
        if (tid < 101)
            *(unsigned*)(slab + swb[4]) = (unsigned)f2bf(a[4]) | ((unsigned)f2bf(b[4]) << 16);
    };

    // ---- K-loop constants ----
    const int lane = tid & 63, wv = tid >> 6;
    const int n16 = lane & 15, hi = lane >> 4;
    const int ct0 = 2 * (wv & 1);
    const int st0 = 2 * (wv >> 1);

    int fpb[2];
#pragma unroll
    for (int tt = 0; tt < 2; ++tt) {
        int sp = (st0 + tt) * 16 + n16;
        int o4l = sp & 7, o3l = (sp >> 3) & 1, o2l = (sp >> 4) & 1, o1l = sp >> 5;
        fpb[tt] = 2 * (1000 * o1l + 200 * o2l + 40 * o3l + 2 * o4l);
    }
    int kof[4][2];
#pragma unroll
    for (int ks = 0; ks < 4; ++ks)
#pragma unroll
    for (int j = 0; j < 2; ++j) {
        int g = 8 * ks + 2 * hi + j;
        if (g > 26) g = 26;                   // zero-weight region
        int k1 = g / 9, k2 = (g / 3) % 3, k3 = g % 3;
        kof[ks][j] = 2 * (500 * k1 + 100 * k2 + 20 * k3);
    }

    auto loadA = [&](int ci, short8 (&Ac)[8]) {
        const unsigned short* aw0 = w1p + (size_t)(ci * 64 + 16 * ct0 + n16) * 136 + hi * 8;
#pragma unroll
        for (int k = 0; k < 4; ++k) Ac[k] = *(const short8*)(aw0 + 32 * k);
        const unsigned short* aw1 = aw0 + 16 * 136;
#pragma unroll
        for (int k = 0; k < 4; ++k) Ac[4 + k] = *(const short8*)(aw1 + 32 * k);
    };
    auto readFR = [&](int s, short8 (&fr)[2][4]) {
        const char* sx = (const char*)sX + s * 5000;
#pragma unroll
        for (int tt = 0; tt < 2; ++tt) {
            const char* base = sx + fpb[tt];
#pragma unroll
            for (int ks = 0; ks < 4; ++ks) {
                unsigned r0 = *(const unsigned*)(base + kof[ks][0]);
                unsigned r1 = *(const unsigned*)(base + kof[ks][0] + 4);
                unsigned r2 = *(const unsigned*)(base + kof[ks][1]);
                unsigned r3 = *(const unsigned*)(base + kof[ks][1] + 4);
                uint4v t = (uint4v){r0, r1, r2, r3};
                fr[tt][ks] = *(short8*)&t;
            }
        }
    };

    f32x4 acc[2][2];
#pragma unroll
    for (int c = 0; c < 2; ++c)
#pragma unroll
    for (int t = 0; t < 2; ++t) acc[c][t] = (f32x4){0.f, 0.f, 0.f, 0.f};

    auto mfma16 = [&](const short8 (&Ac)[8], const short8 (&fr)[2][4]) {
        __builtin_amdgcn_s_setprio(1);
#pragma unroll
        for (int tt = 0; tt < 2; ++tt)
#pragma unroll
        for (int ks = 0; ks < 4; ++ks) {
            acc[0][tt] = __builtin_amdgcn_mfma_f32_16x16x32_bf16(Ac[ks],     fr[tt][ks], acc[0][tt], 0, 0, 0);
            acc[1][tt] = __builtin_amdgcn_mfma_f32_16x16x32_bf16(Ac[4 + ks], fr[tt][ks], acc[1][tt], 0, 0, 0);
        }
        __builtin_amdgcn_s_setprio(0);
    };

    short8 A0[8], A1[8], F0[2][4], F1[2][4];
    // A-frags for first two ci (issued first; land during staging)
    loadA(cb, A0);
    loadA(cb + 1, A1);

    // ---- stage 8 ci (2-deep pipelined) ----
    {
        float a0[5], b0[5], a1[5], b1v[5];
        gatherX(cb, a0, b0);
        gatherX(cb + 1, a1, b1v);
        for (int cc = 0; cc < 8; cc += 2) {
            writeSlab(cc, a0, b0);
            if (cc + 2 < 8) gatherX(cb + cc + 2, a0, b0);
            writeSlab(cc + 1, a1, b1v);
            if (cc + 3 < 8) gatherX(cb + cc + 3, a1, b1v);
        }
    }
    __syncthreads();   // the ONLY barrier

    readFR(0, F0);
    for (int cc = 0; cc < 8; cc += 2) {
        readFR(cc + 1, F1);                   // issue ci+1 B-frags before MFMA(ci)
        mfma16(A0, F0);
        if (cc < 6) { loadA(cb + cc + 2, A0); readFR(cc + 2, F0); }
        mfma16(A1, F1);
        if (cc < 6) loadA(cb + cc + 3, A1);
    }

    // ---- epilogue: fp32 partials -> h32 atomics ----
#pragma unroll
    for (int c = 0; c < 2; ++c) {
#pragma unroll
        for (int tt = 0; tt < 2; ++tt) {
            int spl = 16 * (st0 + tt) + n16;
            int e4 = spl & 7, e3 = (spl >> 3) & 1, e2 = (spl >> 4) & 1, e1 = spl >> 5;
            int sp_lin = (bo1 + e1) * 4096 + (bo2 + e2) * 256 + (bo3 + e3) * 16 + (bo4 + e4);
#pragma unroll
            for (int r = 0; r < 4; ++r) {
                int co = 16 * (ct0 + c) + 4 * hi + r;
                atomicAdd(&h32[(size_t)co * 65536 + sp_lin], acc[c][tt][r]);
            }
        }
    }
}

// ---------------- conv2: barrier-free K-loop, split-K atomics (r18) ---------
// Block: sp 64 = (2,2,2,8) over out 8^4 (64 tiles) x 8 ci-groups (8 ci each).
// Grid 512, 40000 B LDS -> 4 blocks/CU. Wave wv: sp-tile wv, all 16 co.
__global__ __launch_bounds__(256) void conv2_mfma(
        const unsigned short* __restrict__ hpad, const unsigned short* __restrict__ w2p,
        float* __restrict__ out) {
    __shared__ unsigned short sX[20000];   // [ci 8][2500] = 40000 B

    const int tid = threadIdx.x;
    const int braw = blockIdx.x;
    const int bid = ((braw & 7) << 6) | (braw >> 3);   // XCD swizzle, 512 blocks
    const int s = bid & 63, cig = bid >> 6;
    const int t3 = s & 3, t2 = (s >> 2) & 3, t1 = s >> 4;
    const int bo1 = 2 * t1, bo2 = 2 * t2, bo3 = 2 * t3;   // bo4 = 0

    // staging: hpad zero-padded -> no masks, direct u32 copies
    int offs[5], swb[5];
#pragma unroll
    for (int r = 0; r < 5; ++r) {
        int u = tid + 256 * r;
        if (u >= 1125) u = 0;
        int p = u % 9, q = u / 9;
        int i3 = q % 5; q /= 5;
        int i2 = q % 5; int i1 = q / 5;
        offs[r] = (2 * bo1 + i1) * 5832 + (2 * bo2 + i2) * 324 + (2 * bo3 + i3) * 18 + 2 * p;
        swb[r] = 2 * (((i1 * 5 + i2) * 5 + i3) * 20 + 2 * p);
    }

    // ---- stage 8 ci (1-deep pipelined) ----
    {
        unsigned fa[5], na[5];
        const unsigned short* h0 = hpad + (size_t)(cig * 8) * 104976;
#pragma unroll
        for (int r = 0; r < 5; ++r) fa[r] = *(const unsigned*)(h0 + offs[r]);
        for (int s8 = 0; s8 < 8; ++s8) {
            if (s8 < 7) {
                const unsigned short* hc = hpad + (size_t)(cig * 8 + s8 + 1) * 104976;
#pragma unroll
                for (int r = 0; r < 5; ++r) na[r] = *(const unsigned*)(hc + offs[r]);
            }
            char* slab = (char*)sX + s8 * 5000;
#pragma unroll
            for (int r = 0; r < 4; ++r) *(unsigned*)(slab + swb[r]) = fa[r];
            if (tid < 101) *(unsigned*)(slab + swb[4]) = fa[4];
            if (s8 < 7) {
#pragma unroll
                for (int r = 0; r < 5; ++r) fa[r] = na[r];
            }
        }
    }
    __syncthreads();   // the ONLY barrier

    const int lane = tid & 63, wv = tid >> 6;
    const int n16 = lane & 15, hi = lane >> 4;

    int fpb;
    {
        int sp = wv * 16 + n16;
        int o4l = sp & 7, o3l = (sp >> 3) & 1, o2l = (sp >> 4) & 1, o1l = sp >> 5;
        fpb = 2 * (1000 * o1l + 200 * o2l + 40 * o3l + 2 * o4l);
    }
    int kof[4][2];
#pragma unroll
    for (int ks = 0; ks < 4; ++ks)
#pragma unroll
    for (int j = 0; j < 2; ++j) {
        int g = 8 * ks + 2 * hi + j;
        if (g > 26) g = 26;
        int k1 = g / 9, k2 = (g / 3) % 3, k3 = g % 3;
        kof[ks][j] = 2 * (500 * k1 + 100 * k2 + 20 * k3);
    }

    auto loadA = [&](int s8, short8 (&Ac)[4]) {
        const unsigned short* aw = w2p + (size_t)((cig * 8 + s8) * 16 + n16) * 136 + hi * 8;
#pragma unroll
        for (int k = 0; k < 4; ++k) Ac[k] = *(const short8*)(aw + 32 * k);
    };
    auto readFR = [&](int s8, short8 (&fr)[4]) {
        const char* base = (const char*)sX + s8 * 5000 + fpb;
#pragma unroll
        for (int ks = 0; ks < 4; ++ks) {
            unsigned r0 = *(const unsigned*)(base + kof[ks][0]);
            unsigned r1 = *(const unsigned*)(base + kof[ks][0] + 4);
            unsigned r2 = *(const unsigned*)(base + kof[ks][1]);
            unsigned r3 = *(const unsigned*)(base + kof[ks][1] + 4);
            uint4v tmp = (uint4v){r0, r1, r2, r3};
            fr[ks] = *(short8*)&tmp;
        }
    };

    f32x4 acc = (f32x4){0.f, 0.f, 0.f, 0.f};
    short8 A0[4], A1[4], F0[4], F1[4];
    loadA(0, A0);
    loadA(1, A1);
    readFR(0, F0);

    auto mfma4 = [&](const short8 (&Ac)[4], const short8 (&fr)[4]) {
        __builtin_amdgcn_s_setprio(1);
#pragma unroll
        for (int ks = 0; ks < 4; ++ks)
            acc = __builtin_amdgcn_mfma_f32_16x16x32_bf16(Ac[ks], fr[ks], acc, 0, 0, 0);
        __builtin_amdgcn_s_setprio(0);
    };

    for (int cc = 0; cc < 8; cc += 2) {
        readFR(cc + 1, F1);
        mfma4(A0, F0);
        if (cc < 6) { loadA(cc + 2, A0); readFR(cc + 2, F0); }
        mfma4(A1, F1);
        if (cc < 6) loadA(cc + 3, A1);
    }

    {
        int spl = 16 * wv + n16;
        int e4 = spl & 7, e3 = (spl >> 3) & 1, e2 = (spl >> 4) & 1, e1 = spl >> 5;
        int o1 = bo1 + e1, o2 = bo2 + e2, o3 = bo3 + e3, o4 = e4;
#pragma unroll
        for (int r = 0; r < 4; ++r) {
            int co = 4 * hi + r;
            atomicAdd(&out[(size_t)co * 4096 + o1 * 512 + o2 * 64 + o3 * 8 + o4], acc[r]);
        }
    }
}

// ---------------------------------------------------------------------------
extern "C" void kernel_launch(void* const* d_in, const int* in_sizes, int n_in,
                              void* d_out, int out_size, void* d_ws, size_t ws_size,
                              hipStream_t stream) {
    const float* x  = (const float*)d_in[0];
    const float* w1 = (const float*)d_in[1];
    const float* b1 = (const float*)d_in[2];
    const float* w2 = (const float*)d_in[3];
    const float* b2 = (const float*)d_in[4];
    float* out = (float*)d_out;

    unsigned short* hpad = (unsigned short*)d_ws;        // 64*18^4 = 6,718,464 bf16
    unsigned short* w1p  = hpad + 6718464;               // 139,264 bf16
    unsigned short* w2p  = w1p + 139264;                 // 139,264 bf16
    float*          h32  = (float*)(w2p + 139264);       // 4,194,304 fp32 (16 MB)

    setup_kernel<<<8192, 256, 0, stream>>>(w1, w2, b2, w1p, w2p,
                                           (uint4v*)hpad, (uint4v*)h32, out);
    conv1_part<<<2048, 256, 0, stream>>>(x, w1p, h32);
    gelu_pack<<<16384, 256, 0, stream>>>(h32, b1, hpad);
    conv2_mfma<<<512, 256, 0, stream>>>(hpad, w2p, out);
}

// Round 20
// 107.451 us; speedup vs baseline: 1.4018x; 1.4018x over previous
//
#include <hip/hip_runtime.h>
#include <hip/hip_bf16.h>
#include <math.h>

// ---------------------------------------------------------------------------
// MLPConv4d via bf16 MFMA implicit GEMM (v16 = r18 champion + guarded-dwordx2
// staging in conv1; everything else byte-identical to r18).
// conv1: x[16][32^4] fp32 -> hpad[64][18^4] bf16 (GELU'd, zero shell)
// conv2: hpad -> out[16][8^4] fp32 (split-K atomics onto bias-init'd out)
// K layout: k' = grp*4 + k4; grp=(k1*3+k2)*3+k3 < 27. k4=3 slots and k'>=108
// are ZERO in prepacked weights => junk B-reads there are harmless (finite).
// Slab per ci: [i1 5][i2 5][i3 5][i4 20(pad)] bf16 = 2500 shorts (5000 B);
// conv1 16 slabs = 80 KB (2 blocks/CU), conv2 8 slabs = 40 KB (4 blocks/CU).
// B-frag(sp, ks): lane(n16,hi) reads groups g = 8ks+2hi+{0,1} (clamp 26):
//   2x b32 at slab + fpb(sp) + kof(g) + {0,4} (merge->ds_read2_b32).
// K-loop: barrier-free; F ping-pong, A distance-2, setprio around MFMA.
// XCD swizzle on tiled kernels (r18: halved FETCH via L2 sharing).
// conv1 staging: guarded dwordx2 per 2-elem unit — if any-valid: one 8B load
// at clamped offset + boundary select (validated bit-identical in r16);
// fully-invalid units skip the load (no overfetch).
// ---------------------------------------------------------------------------

typedef __attribute__((ext_vector_type(8))) short short8;
typedef __attribute__((ext_vector_type(4))) float f32x4;
typedef __attribute__((ext_vector_type(4))) unsigned int uint4v;
typedef unsigned uint2a __attribute__((ext_vector_type(2), aligned(4)));

__device__ __forceinline__ unsigned short f2bf(float v) {
    __hip_bfloat16 b = __float2bfloat16(v);
    return *(unsigned short*)&b;
}

// ---- fused setup: prepack w1/w2 (zero-padded k'), bias-init out, zero hpad -
__global__ void setup_kernel(const float* __restrict__ w1, const float* __restrict__ w2,
                             const float* __restrict__ b2,
                             unsigned short* __restrict__ w1p, unsigned short* __restrict__ w2p,
                             uint4v* __restrict__ hz, float* __restrict__ out) {
    int b = blockIdx.x, tid = threadIdx.x;
    if (b < 544) {                       // w1p: 16*64*136 = 139264 = 544*256
        int i = b * 256 + tid;
        int kp = i % 136, co = (i / 136) & 63, ci = i / 8704;
        float v = 0.f;
        if (kp < 108 && (kp & 3) < 3) v = w1[(co * 16 + ci) * 81 + (kp >> 2) * 3 + (kp & 3)];
        w1p[i] = f2bf(v);
    } else if (b < 1088) {               // w2p: 64*16*136 = 139264
        int i = (b - 544) * 256 + tid;
        int kp = i % 136, co = (i / 136) & 15, ci = i / 2176;
        float v = 0.f;
        if (kp < 108 && (kp & 3) < 3) v = w2[(co * 64 + ci) * 81 + (kp >> 2) * 3 + (kp & 3)];
        w2p[i] = f2bf(v);
    } else if (b < 1344) {               // out = bias: 65536
        int i = (b - 1088) * 256 + tid;
        out[i] = b2[i >> 12];
    } else {                             // zero hpad: 839808 uint4
        int i = (b - 1344) * 256 + tid;  // 2752*256 = 704512
        hz[i] = (uint4v){0, 0, 0, 0};
        int j = i + 704512;
        if (j < 839808) hz[j] = (uint4v){0, 0, 0, 0};
    }
}

// ---------------- conv1: barrier-free K-loop, 64-sp tiles -------------------
// Block: sp 64 = (o1,o2,o3,o4)=(2,2,2,8), 64 co. Grid 1024, 256 thr, 80 KB.
// Wave wv: sp-tiles 2(wv>>1)+{0,1}, co-tiles 2(wv&1)+{0,1}; 16 MFMA/ci.
__global__ __launch_bounds__(256) void conv1_mfma(
        const float* __restrict__ x, const unsigned short* __restrict__ w1p,
        const float* __restrict__ b1, unsigned short* __restrict__ hpad) {
    __shared__ unsigned short sX[40000];   // [ci 16][2500] = 80000 B

    const int tid = threadIdx.x;
    const int braw = blockIdx.x;
    const int bid = ((braw & 7) << 7) | (braw >> 3);   // XCD swizzle, 1024 blocks
    const int t4 = bid & 1, t3 = (bid >> 1) & 7, t2 = (bid >> 4) & 7, t1 = bid >> 7;
    const int bo1 = 2 * t1, bo2 = 2 * t2, bo3 = 2 * t3, bo4 = 8 * t4;
    const int g1b = 2 * bo1 - 1, g2b = 2 * bo2 - 1, g3b = 2 * bo3 - 1, g4b = 2 * bo4 - 1;

    // ---- staging slots: 1125 2-elem units/ci, u = tid + 256r, r<5 ----
    int offc[5], swb[5];
    unsigned mka = 0, mkb = 0, sA = 0, sB = 0;
#pragma unroll
    for (int r = 0; r < 5; ++r) {
        int u = tid + 256 * r;
        bool uok = u < 1125;
        int uu = uok ? u : 0;
        int p = uu % 9, q = uu / 9;
        int i3 = q % 5; q /= 5;
        int i2 = q % 5; int i1 = q / 5;
        int g1 = g1b + i1, g2 = g2b + i2, g3 = g3b + i3;
        bool ok123 = uok & ((unsigned)g1 < 32u) & ((unsigned)g2 < 32u) & ((unsigned)g3 < 32u);
        int g4a = g4b + 2 * p;
        int o = ((g1 * 32 + g2) * 32 + g3) * 32 + g4a;
        if (ok123 && (unsigned)g4a < 32u) mka |= 1u << r;
        if (ok123 && (unsigned)(g4a + 1) < 32u) mkb |= 1u << r;
        int oc = o < 0 ? 0 : (o > 1048574 ? 1048574 : o);
        if (o > oc) sA |= 1u << r;    // window shifted down: a = v.y
        if (o < oc) sB |= 1u << r;    // window shifted up:   b = v.x
        offc[r] = oc;
        swb[r] = 2 * (((i1 * 5 + i2) * 5 + i3) * 20 + 2 * p);
    }

    auto gatherX = [&](int ci, float (&a)[5], float (&b)[5]) {
        const float* xc = x + (size_t)ci * 1048576;
#pragma unroll
        for (int r = 0; r < 5; ++r) {
            float va = 0.f, vb = 0.f;
            if (((mka | mkb) >> r) & 1) {          // any-valid: one dwordx2
                uint2a v = *(const uint2a*)(xc + offc[r]);
                float lo = __uint_as_float(v.x), hiv = __uint_as_float(v.y);
                float sa = ((sA >> r) & 1) ? hiv : lo;
                float sb = ((sB >> r) & 1) ? lo : hiv;
                va = ((mka >> r) & 1) ? sa : 0.f;
                vb = ((mkb >> r) & 1) ? sb : 0.f;
            }
            a[r] = va; b[r] = vb;
        }
    };
    auto writeSlab = [&](int ci, const float (&a)[5], const float (&b)[5]) {
        char* slab = (char*)sX + ci * 5000;
#pragma unroll
        for (int r = 0; r < 4; ++r)
            *(unsigned*)(slab + swb[r]) = (unsigned)f2bf(a[r]) | ((unsigned)f2bf(b[r]) << 16);
        if (tid < 101)
            *(unsigned*)(slab + swb[4]) = (unsigned)f2bf(a[4]) | ((unsigned)f2bf(b[4]) << 16);
    };

    // ---- K-loop constants ----
    const int lane = tid & 63, wv = tid >> 6;
    const int n16 = lane & 15, hi = lane >> 4;
    const int ct0 = 2 * (wv & 1);
    const int st0 = 2 * (wv >> 1);

    int fpb[2];
#pragma unroll
    for (int tt = 0; tt < 2; ++tt) {
        int sp = (st0 + tt) * 16 + n16;
        int o4l = sp & 7, o3l = (sp >> 3) & 1, o2l = (sp >> 4) & 1, o1l = sp >> 5;
        fpb[tt] = 2 * (1000 * o1l + 200 * o2l + 40 * o3l + 2 * o4l);
    }
    int kof[4][2];
#pragma unroll
    for (int ks = 0; ks < 4; ++ks)
#pragma unroll
    for (int j = 0; j < 2; ++j) {
        int g = 8 * ks + 2 * hi + j;
        if (g > 26) g = 26;                   // zero-weight region
        int k1 = g / 9, k2 = (g / 3) % 3, k3 = g % 3;
        kof[ks][j] = 2 * (500 * k1 + 100 * k2 + 20 * k3);
    }

    auto loadA = [&](int ci, short8 (&Ac)[8]) {
        const unsigned short* aw0 = w1p + (size_t)(ci * 64 + 16 * ct0 + n16) * 136 + hi * 8;
#pragma unroll
        for (int k = 0; k < 4; ++k) Ac[k] = *(const short8*)(aw0 + 32 * k);
        const unsigned short* aw1 = aw0 + 16 * 136;
#pragma unroll
        for (int k = 0; k < 4; ++k) Ac[4 + k] = *(const short8*)(aw1 + 32 * k);
    };
    auto readFR = [&](int ci, short8 (&fr)[2][4]) {
        const char* sx = (const char*)sX + ci * 5000;
#pragma unroll
        for (int tt = 0; tt < 2; ++tt) {
            const char* base = sx + fpb[tt];
#pragma unroll
            for (int ks = 0; ks < 4; ++ks) {
                unsigned r0 = *(const unsigned*)(base + kof[ks][0]);
                unsigned r1 = *(const unsigned*)(base + kof[ks][0] + 4);
                unsigned r2 = *(const unsigned*)(base + kof[ks][1]);
                unsigned r3 = *(const unsigned*)(base + kof[ks][1] + 4);
                uint4v t = (uint4v){r0, r1, r2, r3};
                fr[tt][ks] = *(short8*)&t;
            }
        }
    };

    f32x4 acc[2][2];
#pragma unroll
    for (int c = 0; c < 2; ++c)
#pragma unroll
    for (int t = 0; t < 2; ++t) acc[c][t] = (f32x4){0.f, 0.f, 0.f, 0.f};

    auto mfma16 = [&](const short8 (&Ac)[8], const short8 (&fr)[2][4]) {
        __builtin_amdgcn_s_setprio(1);
#pragma unroll
        for (int tt = 0; tt < 2; ++tt)
#pragma unroll
        for (int ks = 0; ks < 4; ++ks) {
            acc[0][tt] = __builtin_amdgcn_mfma_f32_16x16x32_bf16(Ac[ks],     fr[tt][ks], acc[0][tt], 0, 0, 0);
            acc[1][tt] = __builtin_amdgcn_mfma_f32_16x16x32_bf16(Ac[4 + ks], fr[tt][ks], acc[1][tt], 0, 0, 0);
        }
        __builtin_amdgcn_s_setprio(0);
    };

    short8 A0[8], A1[8], F0[2][4], F1[2][4];
    // A-frags for ci 0,1 (issued first; land during staging)
    loadA(0, A0);
    loadA(1, A1);

    // ---- stage all 16 ci (2-deep pipelined) ----
    {
        float a0[5], b0[5], a1[5], b1v[5];
        gatherX(0, a0, b0);
        gatherX(1, a1, b1v);
        for (int cc = 0; cc < 16; cc += 2) {
            writeSlab(cc, a0, b0);
            if (cc + 2 < 16) gatherX(cc + 2, a0, b0);
            writeSlab(cc + 1, a1, b1v);
            if (cc + 3 < 16) gatherX(cc + 3, a1, b1v);
        }
    }
    __syncthreads();   // the ONLY barrier

    readFR(0, F0);
    for (int cc = 0; cc < 16; cc += 2) {
        readFR(cc + 1, F1);                   // issue ci+1 B-frags before MFMA(ci)
        mfma16(A0, F0);
        if (cc < 14) { loadA(cc + 2, A0); readFR(cc + 2, F0); }
        mfma16(A1, F1);
        if (cc < 14) loadA(cc + 3, A1);
    }

    // ---- epilogue: bias + exact GELU + bf16 store ----
#pragma unroll
    for (int c = 0; c < 2; ++c) {
#pragma unroll
        for (int tt = 0; tt < 2; ++tt) {
            int spl = 16 * (st0 + tt) + n16;
            int e4 = spl & 7, e3 = (spl >> 3) & 1, e2 = (spl >> 4) & 1, e1 = spl >> 5;
            size_t base = (size_t)(bo1 + e1 + 1) * 5832 + (bo2 + e2 + 1) * 324 +
                          (bo3 + e3 + 1) * 18 + (bo4 + e4 + 1);
#pragma unroll
            for (int r = 0; r < 4; ++r) {
                int co = 16 * (ct0 + c) + 4 * hi + r;
                float v = acc[c][tt][r] + b1[co];
                v = 0.5f * v * (1.f + erff(v * 0.70710678118654752f));
                hpad[(size_t)co * 104976 + base] = f2bf(v);
            }
        }
    }
}

// ---------------- conv2: barrier-free K-loop, split-K atomics ---------------
// Block: sp 64 = (2,2,2,8) over out 8^4 (64 tiles) x 8 ci-groups (8 ci each).
// Grid 512, 40000 B LDS -> 4 blocks/CU. Wave wv: sp-tile wv, all 16 co.
__global__ __launch_bounds__(256) void conv2_mfma(
        const unsigned short* __restrict__ hpad, const unsigned short* __restrict__ w2p,
        float* __restrict__ out) {
    __shared__ unsigned short sX[20000];   // [ci 8][2500] = 40000 B

    const int tid = threadIdx.x;
    const int braw = blockIdx.x;
    const int bid = ((braw & 7) << 6) | (braw >> 3);   // XCD swizzle, 512 blocks
    const int s = bid & 63, cig = bid >> 6;
    const int t3 = s & 3, t2 = (s >> 2) & 3, t1 = s >> 4;
    const int bo1 = 2 * t1, bo2 = 2 * t2, bo3 = 2 * t3;   // bo4 = 0

    // staging: hpad zero-padded -> no masks, direct u32 copies
    int offs[5], swb[5];
#pragma unroll
    for (int r = 0; r < 5; ++r) {
        int u = tid + 256 * r;
        if (u >= 1125) u = 0;
        int p = u % 9, q = u / 9;
        int i3 = q % 5; q /= 5;
        int i2 = q % 5; int i1 = q / 5;
        offs[r] = (2 * bo1 + i1) * 5832 + (2 * bo2 + i2) * 324 + (2 * bo3 + i3) * 18 + 2 * p;
        swb[r] = 2 * (((i1 * 5 + i2) * 5 + i3) * 20 + 2 * p);
    }

    // ---- stage 8 ci (1-deep pipelined) ----
    {
        unsigned fa[5], na[5];
        const unsigned short* h0 = hpad + (size_t)(cig * 8) * 104976;
#pragma unroll
        for (int r = 0; r < 5; ++r) fa[r] = *(const unsigned*)(h0 + offs[r]);
        for (int s8 = 0; s8 < 8; ++s8) {
            if (s8 < 7) {
                const unsigned short* hc = hpad + (size_t)(cig * 8 + s8 + 1) * 104976;
#pragma unroll
                for (int r = 0; r < 5; ++r) na[r] = *(const unsigned*)(hc + offs[r]);
            }
            char* slab = (char*)sX + s8 * 5000;
#pragma unroll
            for (int r = 0; r < 4; ++r) *(unsigned*)(slab + swb[r]) = fa[r];
            if (tid < 101) *(unsigned*)(slab + swb[4]) = fa[4];
            if (s8 < 7) {
#pragma unroll
                for (int r = 0; r < 5; ++r) fa[r] = na[r];
            }
        }
    }
    __syncthreads();   // the ONLY barrier

    const int lane = tid & 63, wv = tid >> 6;
    const int n16 = lane & 15, hi = lane >> 4;

    int fpb;
    {
        int sp = wv * 16 + n16;
        int o4l = sp & 7, o3l = (sp >> 3) & 1, o2l = (sp >> 4) & 1, o1l = sp >> 5;
        fpb = 2 * (1000 * o1l + 200 * o2l + 40 * o3l + 2 * o4l);
    }
    int kof[4][2];
#pragma unroll
    for (int ks = 0; ks < 4; ++ks)
#pragma unroll
    for (int j = 0; j < 2; ++j) {
        int g = 8 * ks + 2 * hi + j;
        if (g > 26) g = 26;
        int k1 = g / 9, k2 = (g / 3) % 3, k3 = g % 3;
        kof[ks][j] = 2 * (500 * k1 + 100 * k2 + 20 * k3);
    }

    auto loadA = [&](int s8, short8 (&Ac)[4]) {
        const unsigned short* aw = w2p + (size_t)((cig * 8 + s8) * 16 + n16) * 136 + hi * 8;
#pragma unroll
        for (int k = 0; k < 4; ++k) Ac[k] = *(const short8*)(aw + 32 * k);
    };
    auto readFR = [&](int s8, short8 (&fr)[4]) {
        const char* base = (const char*)sX + s8 * 5000 + fpb;
#pragma unroll
        for (int ks = 0; ks < 4; ++ks) {
            unsigned r0 = *(const unsigned*)(base + kof[ks][0]);
            unsigned r1 = *(const unsigned*)(base + kof[ks][0] + 4);
            unsigned r2 = *(const unsigned*)(base + kof[ks][1]);
            unsigned r3 = *(const unsigned*)(base + kof[ks][1] + 4);
            uint4v tmp = (uint4v){r0, r1, r2, r3};
            fr[ks] = *(short8*)&tmp;
        }
    };

    f32x4 acc = (f32x4){0.f, 0.f, 0.f, 0.f};
    short8 A0[4], A1[4], F0[4], F1[4];
    loadA(0, A0);
    loadA(1, A1);
    readFR(0, F0);

    auto mfma4 = [&](const short8 (&Ac)[4], const short8 (&fr)[4]) {
        __builtin_amdgcn_s_setprio(1);
#pragma unroll
        for (int ks = 0; ks < 4; ++ks)
            acc = __builtin_amdgcn_mfma_f32_16x16x32_bf16(Ac[ks], fr[ks], acc, 0, 0, 0);
        __builtin_amdgcn_s_setprio(0);
    };

    for (int cc = 0; cc < 8; cc += 2) {
        readFR(cc + 1, F1);
        mfma4(A0, F0);
        if (cc < 6) { loadA(cc + 2, A0); readFR(cc + 2, F0); }
        mfma4(A1, F1);
        if (cc < 6) loadA(cc + 3, A1);
    }

    {
        int spl = 16 * wv + n16;
        int e4 = spl & 7, e3 = (spl >> 3) & 1, e2 = (spl >> 4) & 1, e1 = spl >> 5;
        int o1 = bo1 + e1, o2 = bo2 + e2, o3 = bo3 + e3, o4 = e4;
#pragma unroll
        for (int r = 0; r < 4; ++r) {
            int co = 4 * hi + r;
            atomicAdd(&out[(size_t)co * 4096 + o1 * 512 + o2 * 64 + o3 * 8 + o4], acc[r]);
        }
    }
}

// ---------------------------------------------------------------------------
extern "C" void kernel_launch(void* const* d_in, const int* in_sizes, int n_in,
                              void* d_out, int out_size, void* d_ws, size_t ws_size,
                              hipStream_t stream) {
    const float* x  = (const float*)d_in[0];
    const float* w1 = (const float*)d_in[1];
    const float* b1 = (const float*)d_in[2];
    const float* w2 = (const float*)d_in[3];
    const float* b2 = (const float*)d_in[4];
    float* out = (float*)d_out;

    unsigned short* hpad = (unsigned short*)d_ws;        // 64*18^4 = 6,718,464 bf16
    unsigned short* w1p  = hpad + 6718464;               // 139,264 bf16
    unsigned short* w2p  = w1p + 139264;                 // 139,264 bf16

    setup_kernel<<<4096, 256, 0, stream>>>(w1, w2, b2, w1p, w2p, (uint4v*)hpad, out);
    conv1_mfma<<<1024, 256, 0, stream>>>(x, w1p, b1, hpad);
    conv2_mfma<<<512, 256, 0, stream>>>(hpad, w2p, out);
}

// Round 21
// 79.492 us; speedup vs baseline: 1.8949x; 1.3517x over previous
//
#include <hip/hip_runtime.h>
#include <hip/hip_bf16.h>
#include <math.h>

// ---------------------------------------------------------------------------
// MLPConv4d via bf16 MFMA implicit GEMM (v17 = r18 champion, restored verbatim).
// conv1: x[16][32^4] fp32 -> hpad[64][18^4] bf16 (GELU'd, zero shell)
// conv2: hpad -> out[16][8^4] fp32 (split-K atomics onto bias-init'd out)
// K layout: k' = grp*4 + k4; grp=(k1*3+k2)*3+k3 < 27. k4=3 slots and k'>=108
// are ZERO in prepacked weights => junk B-reads there are harmless (finite).
// Slab per ci: [i1 5][i2 5][i3 5][i4 20(pad)] bf16 = 2500 shorts (5000 B);
// conv1 16 slabs = 80 KB (2 blocks/CU), conv2 8 slabs = 40 KB (4 blocks/CU).
// B-frag(sp, ks): lane(n16,hi) reads groups g = 8ks+2hi+{0,1} (clamp 26):
//   2x b32 at slab + fpb(sp) + kof(g) + {0,4} (merge->ds_read2_b32).
// K-loop: barrier-free; F ping-pong, A distance-2, setprio around MFMA.
// XCD swizzle on tiled kernels (halves FETCH via per-XCD L2 tile sharing).
// Staging: masked scalar loads (r16/r20 load-widening variants both regressed:
// clamp+select corrupts boundaries or guard branches serialize the gather).
// ---------------------------------------------------------------------------

typedef __attribute__((ext_vector_type(8))) short short8;
typedef __attribute__((ext_vector_type(4))) float f32x4;
typedef __attribute__((ext_vector_type(4))) unsigned int uint4v;

__device__ __forceinline__ unsigned short f2bf(float v) {
    __hip_bfloat16 b = __float2bfloat16(v);
    return *(unsigned short*)&b;
}

// ---- fused setup: prepack w1/w2 (zero-padded k'), bias-init out, zero hpad -
__global__ void setup_kernel(const float* __restrict__ w1, const float* __restrict__ w2,
                             const float* __restrict__ b2,
                             unsigned short* __restrict__ w1p, unsigned short* __restrict__ w2p,
                             uint4v* __restrict__ hz, float* __restrict__ out) {
    int b = blockIdx.x, tid = threadIdx.x;
    if (b < 544) {                       // w1p: 16*64*136 = 139264 = 544*256
        int i = b * 256 + tid;
        int kp = i % 136, co = (i / 136) & 63, ci = i / 8704;
        float v = 0.f;
        if (kp < 108 && (kp & 3) < 3) v = w1[(co * 16 + ci) * 81 + (kp >> 2) * 3 + (kp & 3)];
        w1p[i] = f2bf(v);
    } else if (b < 1088) {               // w2p: 64*16*136 = 139264
        int i = (b - 544) * 256 + tid;
        int kp = i % 136, co = (i / 136) & 15, ci = i / 2176;
        float v = 0.f;
        if (kp < 108 && (kp & 3) < 3) v = w2[(co * 64 + ci) * 81 + (kp >> 2) * 3 + (kp & 3)];
        w2p[i] = f2bf(v);
    } else if (b < 1344) {               // out = bias: 65536
        int i = (b - 1088) * 256 + tid;
        out[i] = b2[i >> 12];
    } else {                             // zero hpad: 839808 uint4
        int i = (b - 1344) * 256 + tid;  // 2752*256 = 704512
        hz[i] = (uint4v){0, 0, 0, 0};
        int j = i + 704512;
        if (j < 839808) hz[j] = (uint4v){0, 0, 0, 0};
    }
}

// ---------------- conv1: barrier-free K-loop, 64-sp tiles -------------------
// Block: sp 64 = (o1,o2,o3,o4)=(2,2,2,8), 64 co. Grid 1024, 256 thr, 80 KB.
// Wave wv: sp-tiles 2(wv>>1)+{0,1}, co-tiles 2(wv&1)+{0,1}; 16 MFMA/ci.
__global__ __launch_bounds__(256) void conv1_mfma(
        const float* __restrict__ x, const unsigned short* __restrict__ w1p,
        const float* __restrict__ b1, unsigned short* __restrict__ hpad) {
    __shared__ unsigned short sX[40000];   // [ci 16][2500] = 80000 B

    const int tid = threadIdx.x;
    const int braw = blockIdx.x;
    const int bid = ((braw & 7) << 7) | (braw >> 3);   // XCD swizzle, 1024 blocks
    const int t4 = bid & 1, t3 = (bid >> 1) & 7, t2 = (bid >> 4) & 7, t1 = bid >> 7;
    const int bo1 = 2 * t1, bo2 = 2 * t2, bo3 = 2 * t3, bo4 = 8 * t4;
    const int g1b = 2 * bo1 - 1, g2b = 2 * bo2 - 1, g3b = 2 * bo3 - 1, g4b = 2 * bo4 - 1;

    // ---- staging slots: 1125 u32-units/ci (2 i4 elems), u = tid + 256r, r<5
    int offs[5], swb[5];
    unsigned mka = 0, mkb = 0;
#pragma unroll
    for (int r = 0; r < 5; ++r) {
        int u = tid + 256 * r;
        bool uok = u < 1125;
        int uu = uok ? u : 0;
        int p = uu % 9, q = uu / 9;
        int i3 = q % 5; q /= 5;
        int i2 = q % 5; int i1 = q / 5;
        int g1 = g1b + i1, g2 = g2b + i2, g3 = g3b + i3;
        bool ok123 = uok & ((unsigned)g1 < 32u) & ((unsigned)g2 < 32u) & ((unsigned)g3 < 32u);
        int g4a = g4b + 2 * p;
        offs[r] = ((g1 * 32 + g2) * 32 + g3) * 32 + g4a;
        if (ok123 && (unsigned)g4a < 32u) mka |= 1u << r;
        if (ok123 && (unsigned)(g4a + 1) < 32u) mkb |= 1u << r;
        swb[r] = 2 * (((i1 * 5 + i2) * 5 + i3) * 20 + 2 * p);
    }

    auto gatherX = [&](int ci, float (&a)[5], float (&b)[5]) {
        const float* xc = x + (size_t)ci * 1048576;
#pragma unroll
        for (int r = 0; r < 5; ++r) {
            float va = 0.f, vb = 0.f;
            if ((mka >> r) & 1) va = xc[offs[r]];
            if ((mkb >> r) & 1) vb = xc[offs[r] + 1];
            a[r] = va; b[r] = vb;
        }
    };
    auto writeSlab = [&](int ci, const float (&a)[5], const float (&b)[5]) {
        char* slab = (char*)sX + ci * 5000;
#pragma unroll
        for (int r = 0; r < 4; ++r)
            *(unsigned*)(slab + swb[r]) = (unsigned)f2bf(a[r]) | ((unsigned)f2bf(b[r]) << 16);
        if (tid < 101)
            *(unsigned*)(slab + swb[4]) = (unsigned)f2bf(a[4]) | ((unsigned)f2bf(b[4]) << 16);
    };

    // ---- K-loop constants ----
    const int lane = tid & 63, wv = tid >> 6;
    const int n16 = lane & 15, hi = lane >> 4;
    const int ct0 = 2 * (wv & 1);
    const int st0 = 2 * (wv >> 1);

    int fpb[2];
#pragma unroll
    for (int tt = 0; tt < 2; ++tt) {
        int sp = (st0 + tt) * 16 + n16;
        int o4l = sp & 7, o3l = (sp >> 3) & 1, o2l = (sp >> 4) & 1, o1l = sp >> 5;
        fpb[tt] = 2 * (1000 * o1l + 200 * o2l + 40 * o3l + 2 * o4l);
    }
    int kof[4][2];
#pragma unroll
    for (int ks = 0; ks < 4; ++ks)
#pragma unroll
    for (int j = 0; j < 2; ++j) {
        int g = 8 * ks + 2 * hi + j;
        if (g > 26) g = 26;                   // zero-weight region
        int k1 = g / 9, k2 = (g / 3) % 3, k3 = g % 3;
        kof[ks][j] = 2 * (500 * k1 + 100 * k2 + 20 * k3);
    }

    auto loadA = [&](int ci, short8 (&Ac)[8]) {
        const unsigned short* aw0 = w1p + (size_t)(ci * 64 + 16 * ct0 + n16) * 136 + hi * 8;
#pragma unroll
        for (int k = 0; k < 4; ++k) Ac[k] = *(const short8*)(aw0 + 32 * k);
        const unsigned short* aw1 = aw0 + 16 * 136;
#pragma unroll
        for (int k = 0; k < 4; ++k) Ac[4 + k] = *(const short8*)(aw1 + 32 * k);
    };
    auto readFR = [&](int ci, short8 (&fr)[2][4]) {
        const char* sx = (const char*)sX + ci * 5000;
#pragma unroll
        for (int tt = 0; tt < 2; ++tt) {
            const char* base = sx + fpb[tt];
#pragma unroll
            for (int ks = 0; ks < 4; ++ks) {
                unsigned r0 = *(const unsigned*)(base + kof[ks][0]);
                unsigned r1 = *(const unsigned*)(base + kof[ks][0] + 4);
                unsigned r2 = *(const unsigned*)(base + kof[ks][1]);
                unsigned r3 = *(const unsigned*)(base + kof[ks][1] + 4);
                uint4v t = (uint4v){r0, r1, r2, r3};
                fr[tt][ks] = *(short8*)&t;
            }
        }
    };

    f32x4 acc[2][2];
#pragma unroll
    for (int c = 0; c < 2; ++c)
#pragma unroll
    for (int t = 0; t < 2; ++t) acc[c][t] = (f32x4){0.f, 0.f, 0.f, 0.f};

    auto mfma16 = [&](const short8 (&Ac)[8], const short8 (&fr)[2][4]) {
        __builtin_amdgcn_s_setprio(1);
#pragma unroll
        for (int tt = 0; tt < 2; ++tt)
#pragma unroll
        for (int ks = 0; ks < 4; ++ks) {
            acc[0][tt] = __builtin_amdgcn_mfma_f32_16x16x32_bf16(Ac[ks],     fr[tt][ks], acc[0][tt], 0, 0, 0);
            acc[1][tt] = __builtin_amdgcn_mfma_f32_16x16x32_bf16(Ac[4 + ks], fr[tt][ks], acc[1][tt], 0, 0, 0);
        }
        __builtin_amdgcn_s_setprio(0);
    };

    short8 A0[8], A1[8], F0[2][4], F1[2][4];
    // A-frags for ci 0,1 (issued first; land during staging)
    loadA(0, A0);
    loadA(1, A1);

    // ---- stage all 16 ci (2-deep pipelined) ----
    {
        float a0[5], b0[5], a1[5], b1v[5];
        gatherX(0, a0, b0);
        gatherX(1, a1, b1v);
        for (int cc = 0; cc < 16; cc += 2) {
            writeSlab(cc, a0, b0);
            if (cc + 2 < 16) gatherX(cc + 2, a0, b0);
            writeSlab(cc + 1, a1, b1v);
            if (cc + 3 < 16) gatherX(cc + 3, a1, b1v);
        }
    }
    __syncthreads();   // the ONLY barrier

    readFR(0, F0);
    for (int cc = 0; cc < 16; cc += 2) {
        readFR(cc + 1, F1);                   // issue ci+1 B-frags before MFMA(ci)
        mfma16(A0, F0);
        if (cc < 14) { loadA(cc + 2, A0); readFR(cc + 2, F0); }
        mfma16(A1, F1);
        if (cc < 14) loadA(cc + 3, A1);
    }

    // ---- epilogue: bias + exact GELU + bf16 store ----
#pragma unroll
    for (int c = 0; c < 2; ++c) {
#pragma unroll
        for (int tt = 0; tt < 2; ++tt) {
            int spl = 16 * (st0 + tt) + n16;
            int e4 = spl & 7, e3 = (spl >> 3) & 1, e2 = (spl >> 4) & 1, e1 = spl >> 5;
            size_t base = (size_t)(bo1 + e1 + 1) * 5832 + (bo2 + e2 + 1) * 324 +
                          (bo3 + e3 + 1) * 18 + (bo4 + e4 + 1);
#pragma unroll
            for (int r = 0; r < 4; ++r) {
                int co = 16 * (ct0 + c) + 4 * hi + r;
                float v = acc[c][tt][r] + b1[co];
                v = 0.5f * v * (1.f + erff(v * 0.70710678118654752f));
                hpad[(size_t)co * 104976 + base] = f2bf(v);
            }
        }
    }
}

// ---------------- conv2: barrier-free K-loop, split-K atomics ---------------
// Block: sp 64 = (2,2,2,8) over out 8^4 (64 tiles) x 8 ci-groups (8 ci each).
// Grid 512, 40000 B LDS -> 4 blocks/CU. Wave wv: sp-tile wv, all 16 co.
__global__ __launch_bounds__(256) void conv2_mfma(
        const unsigned short* __restrict__ hpad, const unsigned short* __restrict__ w2p,
        float* __restrict__ out) {
    __shared__ unsigned short sX[20000];   // [ci 8][2500] = 40000 B

    const int tid = threadIdx.x;
    const int braw = blockIdx.x;
    const int bid = ((braw & 7) << 6) | (braw >> 3);   // XCD swizzle, 512 blocks
    const int s = bid & 63, cig = bid >> 6;
    const int t3 = s & 3, t2 = (s >> 2) & 3, t1 = s >> 4;
    const int bo1 = 2 * t1, bo2 = 2 * t2, bo3 = 2 * t3;   // bo4 = 0

    // staging: hpad zero-padded -> no masks, direct u32 copies
    int offs[5], swb[5];
#pragma unroll
    for (int r = 0; r < 5; ++r) {
        int u = tid + 256 * r;
        if (u >= 1125) u = 0;
        int p = u % 9, q = u / 9;
        int i3 = q % 5; q /= 5;
        int i2 = q % 5; int i1 = q / 5;
        offs[r] = (2 * bo1 + i1) * 5832 + (2 * bo2 + i2) * 324 + (2 * bo3 + i3) * 18 + 2 * p;
        swb[r] = 2 * (((i1 * 5 + i2) * 5 + i3) * 20 + 2 * p);
    }

    // ---- stage 8 ci (1-deep pipelined) ----
    {
        unsigned fa[5], na[5];
        const unsigned short* h0 = hpad + (size_t)(cig * 8) * 104976;
#pragma unroll
        for (int r = 0; r < 5; ++r) fa[r] = *(const unsigned*)(h0 + offs[r]);
        for (int s8 = 0; s8 < 8; ++s8) {
            if (s8 < 7) {
                const unsigned short* hc = hpad + (size_t)(cig * 8 + s8 + 1) * 104976;
#pragma unroll
                for (int r = 0; r < 5; ++r) na[r] = *(const unsigned*)(hc + offs[r]);
            }
            char* slab = (char*)sX + s8 * 5000;
#pragma unroll
            for (int r = 0; r < 4; ++r) *(unsigned*)(slab + swb[r]) = fa[r];
            if (tid < 101) *(unsigned*)(slab + swb[4]) = fa[4];
            if (s8 < 7) {
#pragma unroll
                for (int r = 0; r < 5; ++r) fa[r] = na[r];
            }
        }
    }
    __syncthreads();   // the ONLY barrier

    const int lane = tid & 63, wv = tid >> 6;
    const int n16 = lane & 15, hi = lane >> 4;

    int fpb;
    {
        int sp = wv * 16 + n16;
        int o4l = sp & 7, o3l = (sp >> 3) & 1, o2l = (sp >> 4) & 1, o1l = sp >> 5;
        fpb = 2 * (1000 * o1l + 200 * o2l + 40 * o3l + 2 * o4l);
    }
    int kof[4][2];
#pragma unroll
    for (int ks = 0; ks < 4; ++ks)
#pragma unroll
    for (int j = 0; j < 2; ++j) {
        int g = 8 * ks + 2 * hi + j;
        if (g > 26) g = 26;
        int k1 = g / 9, k2 = (g / 3) % 3, k3 = g % 3;
        kof[ks][j] = 2 * (500 * k1 + 100 * k2 + 20 * k3);
    }

    auto loadA = [&](int s8, short8 (&Ac)[4]) {
        const unsigned short* aw = w2p + (size_t)((cig * 8 + s8) * 16 + n16) * 136 + hi * 8;
#pragma unroll
        for (int k = 0; k < 4; ++k) Ac[k] = *(const short8*)(aw + 32 * k);
    };
    auto readFR = [&](int s8, short8 (&fr)[4]) {
        const char* base = (const char*)sX + s8 * 5000 + fpb;
#pragma unroll
        for (int ks = 0; ks < 4; ++ks) {
            unsigned r0 = *(const unsigned*)(base + kof[ks][0]);
            unsigned r1 = *(const unsigned*)(base + kof[ks][0] + 4);
            unsigned r2 = *(const unsigned*)(base + kof[ks][1]);
            unsigned r3 = *(const unsigned*)(base + kof[ks][1] + 4);
            uint4v tmp = (uint4v){r0, r1, r2, r3};
            fr[ks] = *(short8*)&tmp;
        }
    };

    f32x4 acc = (f32x4){0.f, 0.f, 0.f, 0.f};
    short8 A0[4], A1[4], F0[4], F1[4];
    loadA(0, A0);
    loadA(1, A1);
    readFR(0, F0);

    auto mfma4 = [&](const short8 (&Ac)[4], const short8 (&fr)[4]) {
        __builtin_amdgcn_s_setprio(1);
#pragma unroll
        for (int ks = 0; ks < 4; ++ks)
            acc = __builtin_amdgcn_mfma_f32_16x16x32_bf16(Ac[ks], fr[ks], acc, 0, 0, 0);
        __builtin_amdgcn_s_setprio(0);
    };

    for (int cc = 0; cc < 8; cc += 2) {
        readFR(cc + 1, F1);
        mfma4(A0, F0);
        if (cc < 6) { loadA(cc + 2, A0); readFR(cc + 2, F0); }
        mfma4(A1, F1);
        if (cc < 6) loadA(cc + 3, A1);
    }

    {
        int spl = 16 * wv + n16;
        int e4 = spl & 7, e3 = (spl >> 3) & 1, e2 = (spl >> 4) & 1, e1 = spl >> 5;
        int o1 = bo1 + e1, o2 = bo2 + e2, o3 = bo3 + e3, o4 = e4;
#pragma unroll
        for (int r = 0; r < 4; ++r) {
            int co = 4 * hi + r;
            atomicAdd(&out[(size_t)co * 4096 + o1 * 512 + o2 * 64 + o3 * 8 + o4], acc[r]);
        }
    }
}

// ---------------------------------------------------------------------------
extern "C" void kernel_launch(void* const* d_in, const int* in_sizes, int n_in,
                              void* d_out, int out_size, void* d_ws, size_t ws_size,
                              hipStream_t stream) {
    const float* x  = (const float*)d_in[0];
    const float* w1 = (const float*)d_in[1];
    const float* b1 = (const float*)d_in[2];
    const float* w2 = (const float*)d_in[3];
    const float* b2 = (const float*)d_in[4];
    float* out = (float*)d_out;

    unsigned short* hpad = (unsigned short*)d_ws;        // 64*18^4 = 6,718,464 bf16
    unsigned short* w1p  = hpad + 6718464;               // 139,264 bf16
    unsigned short* w2p  = w1p + 139264;                 // 139,264 bf16

    setup_kernel<<<4096, 256, 0, stream>>>(w1, w2, b2, w1p, w2p, (uint4v*)hpad, out);
    conv1_mfma<<<1024, 256, 0, stream>>>(x, w1p, b1, hpad);
    conv2_mfma<<<512, 256, 0, stream>>>(hpad, w2p, out);
}